// Round 6
// baseline (57.396 us; speedup 1.0000x reference)
//
#include <hip/hip_runtime.h>
#include <hip/hip_bf16.h>

// Chamfer via MFMA, operand-swapped: D_nm = |x_n - y_m|^2, K=16 fp16-split.
//   a(x) = [xh0..2, xl0..2, xh0..2, 1, 1, xxh, xxl, 0,0,0]      (A operand, STAGED reduce pts)
//   b(y) = [-2yh0..2, -2yh0..2, -2yl0..2, yyh, yyl, 1, 1, 0,0,0] (B operand, REGISTER output pts)
// C layout (32x32): col=lane&31 -> OUTPUT point, row=(r&3)+8*(r>>2)+4*kh -> REDUCE point.
// => per MFMA: tree-min the 16 accs into one per-lane scalar rb[t]. rb = 4 regs
//    (was 32) -> whole working set fits VGPRs, no AGPR<->VGPR move traffic.
// Final: one shfl_xor(32) folds the two kh-halves of the reduce dim.
// Double-buffered 16KB LDS chunks + register prefetch hides staging.

typedef _Float16 f16x8 __attribute__((ext_vector_type(8)));
typedef float f32x16 __attribute__((ext_vector_type(16)));

#define NPTS 8192
#define BATCH 8
#define TPB 512
#define T_OUT 4                      // output tiles per wave
#define OPB 1024                     // output pts per block = 8 waves * T_OUT * 32
#define NRS 4                        // reduce-dim splits
#define RED_PER_BLK (NPTS / NRS)     // 2048
#define CHUNK 512                    // reduce pts per LDS chunk
#define NCH (RED_PER_BLK / CHUNK)    // 4
#define ATILES (CHUNK / 32)          // 16
#define NQ_TOT (2 * BATCH * NPTS)    // 131072

__device__ __forceinline__ void cvt_split(float v, _Float16& h, _Float16& l) {
    h = (_Float16)v; l = (_Float16)(v - (float)h);
}

__device__ __forceinline__ void aform(float x0, float x1, float x2,
                                      f16x8& lo, f16x8& hi) {
    _Float16 h0, l0, h1, l1, h2, l2;
    cvt_split(x0, h0, l0); cvt_split(x1, h1, l1); cvt_split(x2, h2, l2);
    const float xx = x0 * x0 + x1 * x1 + x2 * x2;
    _Float16 xxh, xxl; cvt_split(xx, xxh, xxl);
    lo = f16x8{ h0, h1, h2, l0, l1, l2, h0, h1 };
    hi = f16x8{ h2, (_Float16)1, (_Float16)1, xxh, xxl,
                (_Float16)0, (_Float16)0, (_Float16)0 };
}

__device__ __forceinline__ void bform(float y0, float y1, float y2,
                                      f16x8& lo, f16x8& hi) {
    _Float16 h0, l0, h1, l1, h2, l2;
    { const float hf = (float)(_Float16)y0; h0 = (_Float16)(-2.f * hf); l0 = (_Float16)(-2.f * (y0 - hf)); }
    { const float hf = (float)(_Float16)y1; h1 = (_Float16)(-2.f * hf); l1 = (_Float16)(-2.f * (y1 - hf)); }
    { const float hf = (float)(_Float16)y2; h2 = (_Float16)(-2.f * hf); l2 = (_Float16)(-2.f * (y2 - hf)); }
    const float yy = y0 * y0 + y1 * y1 + y2 * y2;
    _Float16 yyh, yyl; cvt_split(yy, yyh, yyl);
    lo = f16x8{ h0, h1, h2, h0, h1, h2, l0, l1 };
    hi = f16x8{ l2, yyh, yyl, (_Float16)1, (_Float16)1,
                (_Float16)0, (_Float16)0, (_Float16)0 };
}

__device__ __forceinline__ float min16(const f32x16 a) {
    const float m0 = fminf(a[0], a[1]),   m1 = fminf(a[2], a[3]);
    const float m2 = fminf(a[4], a[5]),   m3 = fminf(a[6], a[7]);
    const float m4 = fminf(a[8], a[9]),   m5 = fminf(a[10], a[11]);
    const float m6 = fminf(a[12], a[13]), m7 = fminf(a[14], a[15]);
    const float n0 = fminf(m0, m1), n1 = fminf(m2, m3);
    const float n2 = fminf(m4, m5), n3 = fminf(m6, m7);
    return fminf(fminf(n0, n1), fminf(n2, n3));
}

__global__ __launch_bounds__(TPB, 4) void chamfer_mfma_kernel(
    const float* __restrict__ preds, const float* __restrict__ gts,
    float* __restrict__ partial /* [2][BATCH][NPTS][NRS] */)
{
    __shared__ f16x8 ldsA[2][ATILES][2][32];   // 32 KB total (two 16KB buffers)

    const int bid  = blockIdx.x;               // 512 blocks
    const int pass = bid >> 8;
    const int b    = (bid >> 5) & 7;
    const int ob   = (bid >> 2) & 7;           // 8 output blocks
    const int rs   = bid & 3;                  // 4 reduce splits

    // pass 0: outputs = preds (loss_1 queries), reduce = gts; pass 1 swapped.
    const float* __restrict__ Osrc = (pass == 0) ? preds : gts;
    const float* __restrict__ Rsrc = (pass == 0) ? gts : preds;
    const float* __restrict__ Ob = Osrc + (size_t)b * NPTS * 3;
    const float* __restrict__ Rb = Rsrc + (size_t)b * NPTS * 3;

    const int tid  = threadIdx.x;
    const int lane = tid & 63;
    const int w    = tid >> 6;                 // 8 waves
    const int kh   = lane >> 5;
    const int cl   = lane & 31;

    // --- B fragments: this wave's T_OUT*32 output points, resident all kernel ---
    f16x8 bf[T_OUT];
#pragma unroll
    for (int t = 0; t < T_OUT; ++t) {
        const int opt = ob * OPB + (w * T_OUT + t) * 32 + cl;
        const float* yp = Ob + (size_t)opt * 3;
        f16x8 lo, hi; bform(yp[0], yp[1], yp[2], lo, hi);
        bf[t] = kh ? hi : lo;
    }

    const f32x16 zc = {};
    float rb0 = 1e30f, rb1 = 1e30f, rb2 = 1e30f, rb3 = 1e30f;

    // --- prologue: stage chunk 0 (1 reduce pt per thread) ---
    {
        const float* rp = Rb + (size_t)(rs * RED_PER_BLK + tid) * 3;
        f16x8 lo, hi; aform(rp[0], rp[1], rp[2], lo, hi);
        ldsA[0][tid >> 5][0][tid & 31] = lo;
        ldsA[0][tid >> 5][1][tid & 31] = hi;
    }
    __syncthreads();

    for (int c = 0; c < NCH; ++c) {
        // prefetch next chunk's point into registers (latency hides under MFMA)
        float g0 = 0.f, g1 = 0.f, g2 = 0.f;
        if (c + 1 < NCH) {
            const float* rp = Rb + (size_t)(rs * RED_PER_BLK + (c + 1) * CHUNK + tid) * 3;
            g0 = rp[0]; g1 = rp[1]; g2 = rp[2];
        }

        const f16x8* __restrict__ abase = &ldsA[c & 1][0][kh][cl];
#pragma unroll 4
        for (int at = 0; at < ATILES; ++at) {
            const f16x8 af = abase[at * 64];   // atile stride = 2*32 f16x8
            const f32x16 a0 = __builtin_amdgcn_mfma_f32_32x32x16_f16(af, bf[0], zc, 0, 0, 0);
            const f32x16 a1 = __builtin_amdgcn_mfma_f32_32x32x16_f16(af, bf[1], zc, 0, 0, 0);
            rb0 = fminf(rb0, min16(a0));
            rb1 = fminf(rb1, min16(a1));
            const f32x16 a2 = __builtin_amdgcn_mfma_f32_32x32x16_f16(af, bf[2], zc, 0, 0, 0);
            const f32x16 a3 = __builtin_amdgcn_mfma_f32_32x32x16_f16(af, bf[3], zc, 0, 0, 0);
            rb2 = fminf(rb2, min16(a2));
            rb3 = fminf(rb3, min16(a3));
        }

        if (c + 1 < NCH) {
            f16x8 lo, hi; aform(g0, g1, g2, lo, hi);
            ldsA[(c + 1) & 1][tid >> 5][0][tid & 31] = lo;
            ldsA[(c + 1) & 1][tid >> 5][1][tid & 31] = hi;
        }
        __syncthreads();
    }

    // --- fold the two kh lane-halves (complementary reduce rows), store ---
    float rbv[T_OUT] = { rb0, rb1, rb2, rb3 };
    const size_t qbase = (size_t)(pass * BATCH + b) * NPTS;
#pragma unroll
    for (int t = 0; t < T_OUT; ++t) {
        const float v = fminf(rbv[t], __shfl_xor(rbv[t], 32, 64));
        if (kh == 0) {
            const int opt = ob * OPB + (w * T_OUT + t) * 32 + cl;
            partial[(qbase + opt) * NRS + rs] = v;
        }
    }
}

// Stage 2: min over NRS partials per query, sum -> 512 block sums
__global__ __launch_bounds__(256) void chamfer_reduce1(
    const float* __restrict__ partial, float* __restrict__ bsums)
{
    const int gid = blockIdx.x * 256 + threadIdx.x;   // one query per thread
    const float4 v = ((const float4*)partial)[gid];
    float m = fminf(fminf(v.x, v.y), fminf(v.z, v.w));

#pragma unroll
    for (int off = 32; off > 0; off >>= 1) m += __shfl_down(m, off, 64);

    __shared__ float wsum[4];
    const int lane = threadIdx.x & 63;
    const int wid  = threadIdx.x >> 6;
    if (lane == 0) wsum[wid] = m;
    __syncthreads();
    if (threadIdx.x == 0)
        bsums[blockIdx.x] = (wsum[0] + wsum[1]) + (wsum[2] + wsum[3]);
}

// Stage 3: sum 512 block sums, scale, write scalar
__global__ __launch_bounds__(512) void chamfer_reduce2(
    const float* __restrict__ bsums, float* __restrict__ out)
{
    float m = bsums[threadIdx.x];
#pragma unroll
    for (int off = 32; off > 0; off >>= 1) m += __shfl_down(m, off, 64);

    __shared__ float wsum[8];
    const int lane = threadIdx.x & 63;
    const int wid  = threadIdx.x >> 6;
    if (lane == 0) wsum[wid] = m;
    __syncthreads();
    if (threadIdx.x == 0) {
        float t = ((wsum[0] + wsum[1]) + (wsum[2] + wsum[3]))
                + ((wsum[4] + wsum[5]) + (wsum[6] + wsum[7]));
        out[0] = t * (1.0f / 65536.0f);
    }
}

extern "C" void kernel_launch(void* const* d_in, const int* in_sizes, int n_in,
                              void* d_out, int out_size, void* d_ws, size_t ws_size,
                              hipStream_t stream) {
    const float* preds = (const float*)d_in[0];   // [8, 8192, 3]
    const float* gts   = (const float*)d_in[1];   // [8, 8192, 3]
    float* out = (float*)d_out;

    float* partial = (float*)d_ws;   // 131072*4 floats = 2 MB, fully overwritten
    float* bsums   = (float*)((char*)d_ws + (size_t)NQ_TOT * NRS * sizeof(float));

    chamfer_mfma_kernel<<<512, TPB, 0, stream>>>(preds, gts, partial);
    chamfer_reduce1<<<512, 256, 0, stream>>>(partial, bsums);
    chamfer_reduce2<<<1, 512, 0, stream>>>(bsums, out);
}